// Round 1
// baseline (324.116 us; speedup 1.0000x reference)
//
#include <hip/hip_runtime.h>
#include <cstdint>

// Column1: 512 independent (32x2048)@(2048x32) fp32 GEMMs + per-branch kWTA epilogue.
// Memory-bound: 270 MB / launch -> ~43 us floor at 6.3 TB/s.
// One block per branch r. Double-buffered LDS (2 x 64 rows x 128 floats = 64 KB),
// XOR-swizzled layout (no padding -> fits exactly, conflict-free b128 reads).

#define RFN 512
#define TN  32
#define KN  32
#define LN  2048
#define CHUNK 128
#define NITER (LN / CHUNK)   // 16

__global__ __launch_bounds__(256, 2) void column1_kernel(
    const float* __restrict__ rec,   // (T=32, C=1, RF=512, L=2048)
    const float* __restrict__ wgt,   // (RF=512, K=32, C=1, L=2048)
    float* __restrict__ out)         // (T=32, 1, K=32, RF=512)
{
    __shared__ __align__(16) float lds[2 * 64 * CHUNK];  // 65536 B exactly
    const int r    = blockIdx.x;
    const int tid  = threadIdx.x;
    const int lane = tid & 63;
    const int wv   = tid >> 6;       // wave 0..3: splits l 4-ways
    const int tg   = lane >> 3;      // 0..7 : owns t in {tg, tg+8, tg+16, tg+24}
    const int kg   = lane & 7;       // 0..7 : owns k in {kg, kg+8, kg+16, kg+24}

    // ---- staging plan: 8 float4 per thread; rows r0+8s (0..31 rec-t, 32..63 w-k), quad c4
    const int c4 = tid & 31;
    const int r0 = tid >> 5;
    const float* gsrc[8];
    int ldoff[8];
#pragma unroll
    for (int s = 0; s < 8; ++s) {
        const int row = r0 + 8 * s;                 // 0..63
        const float* g;
        if (row < 32) g = rec + ((size_t)(row * RFN + r)) * LN + (c4 << 2);
        else          g = wgt + ((size_t)(r * KN + (row - 32))) * LN + (c4 << 2);
        gsrc[s]  = g;
        // XOR swizzle: quad position c4 stored at c4 ^ (row & 7) -> conflict-free reads, no pad
        ldoff[s] = row * CHUNK + ((c4 ^ (row & 7)) << 2);
    }

    // prefetch chunk 0 into registers
    float4 stage[8];
#pragma unroll
    for (int s = 0; s < 8; ++s) stage[s] = *(const float4*)gsrc[s];

    float acc[4][4];
#pragma unroll
    for (int jt = 0; jt < 4; ++jt)
#pragma unroll
        for (int jk = 0; jk < 4; ++jk) acc[jt][jk] = 0.0f;

    int p = 0;
    for (int it = 0; it < NITER; ++it) {
        float* buf = lds + p * (64 * CHUNK);
        // commit prefetched chunk to LDS (waits vmcnt on the global loads)
#pragma unroll
        for (int s = 0; s < 8; ++s) *(float4*)(buf + ldoff[s]) = stage[s];
        __syncthreads();   // single barrier per chunk (double-buffer makes it safe)
        // issue next chunk's global loads early -> a full compute phase of latency hiding
        if (it + 1 < NITER) {
#pragma unroll
            for (int s = 0; s < 8; ++s) {
                gsrc[s] += CHUNK;
                stage[s] = *(const float4*)gsrc[s];
            }
        }
        const float* rs = buf;
        const float* ws = buf + 32 * CHUNK;
#pragma unroll
        for (int q = 0; q < 8; ++q) {
            const int qg = (wv << 3) + q;           // this wave's l-quad within the chunk
            float4 a[4], b[4];
#pragma unroll
            for (int j = 0; j < 4; ++j)
                a[j] = *(const float4*)(rs + (tg + 8 * j) * CHUNK + ((qg ^ tg) << 2));
#pragma unroll
            for (int j = 0; j < 4; ++j)
                b[j] = *(const float4*)(ws + (kg + 8 * j) * CHUNK + ((qg ^ kg) << 2));
#pragma unroll
            for (int jt = 0; jt < 4; ++jt)
#pragma unroll
                for (int jk = 0; jk < 4; ++jk) {
                    float v0 = fmaf(a[jt].x, b[jk].x, acc[jt][jk]);
                    v0 = fmaf(a[jt].y, b[jk].y, v0);
                    v0 = fmaf(a[jt].z, b[jk].z, v0);
                    acc[jt][jk] = fmaf(a[jt].w, b[jk].w, v0);
                }
        }
        p ^= 1;
    }

    // ---- cross-wave reduction. Scratch lives in buffer-0 region (lds[0..8191]);
    // after the final barrier every thread is at/after compute(15), which reads buffer 1 -> safe.
    float* red = lds;                                // 4 x 1024 floats
#pragma unroll
    for (int jt = 0; jt < 4; ++jt)
#pragma unroll
        for (int jk = 0; jk < 4; ++jk)
            red[(wv << 10) + (tg + 8 * jt) * 32 + (kg + 8 * jk)] = acc[jt][jk];
    __syncthreads();

    float* thr_s = lds + 4096;                       // 32 x 33 (padded)
#pragma unroll
    for (int e = 0; e < 4; ++e) {
        const int o = (tid << 2) + e;                // flat (t,k), 4 per thread
        float pv = red[o] + red[1024 + o] + red[2048 + o] + red[3072 + o];
        float th = (pv > 20.0f) ? pv : 0.0f;         // sf.fire: strictly-greater threshold
        thr_s[(o >> 5) * 33 + (o & 31)] = th;
    }
    __syncthreads();

    float* nspk_s = lds + 4096 + 1056;
    float* vals_s = nspk_s + 32;
    float* cand_s = vals_s + 32;
    float* tot_s  = cand_s + 32;
    float* mask_s = tot_s + 32;

    if (tid < 32) {
        const int k = tid;
        int ns = 0;
        for (int t = 0; t < 32; ++t) ns += (thr_s[t * 33 + k] > 0.0f) ? 1 : 0;
        int first = 32 - ns; if (first > 31) first = 31;   // clip(T - nspk, 0, T-1)
        const float vf = thr_s[first * 33 + k];
        nspk_s[k] = (float)ns;
        vals_s[k] = vf;
        cand_s[k] = (ns > 0) ? vf : 0.0f;            // max_t spikes*vals per k
        mask_s[k] = 0.0f;
    }
    __syncthreads();

    if (tid == 0) {
        float vm = 0.0f;
        for (int k = 0; k < 32; ++k) vm = fmaxf(vm, cand_s[k]);
        const float v = vm * 32.0f;                  // trunc.max() * T
        for (int k = 0; k < 32; ++k) tot_s[k] = nspk_s[k] * (vals_s[k] + v);
        // top-4, ties -> lower index (matches lax.top_k); winner valid iff total != 0
        for (int sel = 0; sel < 4; ++sel) {
            int best = 0; float bv = -1.0f;
            for (int k = 0; k < 32; ++k) {
                const float tv = tot_s[k];
                if (tv > bv) { bv = tv; best = k; }
            }
            if (bv > 0.0f) mask_s[best] = 1.0f;
            tot_s[best] = -1.0f;
        }
    }
    __syncthreads();

    // out[t,0,k,r] = spike[t,k] & mask[k]
#pragma unroll
    for (int e = 0; e < 4; ++e) {
        const int o = (tid << 2) + e;
        const int t = o >> 5, k = o & 31;
        out[(size_t)t * (KN * RFN) + k * RFN + r] =
            (thr_s[t * 33 + k] > 0.0f && mask_s[k] > 0.0f) ? 1.0f : 0.0f;
    }
}

extern "C" void kernel_launch(void* const* d_in, const int* in_sizes, int n_in,
                              void* d_out, int out_size, void* d_ws, size_t ws_size,
                              hipStream_t stream) {
    const float* rec = (const float*)d_in[0];   // rec_field (32,1,512,2048)
    const float* wgt = (const float*)d_in[1];   // W         (512,32,1,2048)
    // d_in[2] = reward: unused by the forward output
    float* out = (float*)d_out;                 // (32,1,32,512)
    column1_kernel<<<dim3(RFN), dim3(256), 0, stream>>>(rec, wgt, out);
}